// Round 12
// baseline (543.960 us; speedup 1.0000x reference)
//
#include <hip/hip_runtime.h>
#include <math.h>

#define NNODES 50000
#define NEDGES 250000
#define NREL   9
#define F_IN   128
#define HID    256
#define F_OUT  128
#define RN     (NREL * NNODES)
#define RE     (NREL * NEDGES)
#define MPAD   50048              // 391*128
#define K1     (NREL * F_IN)      // 1152
#define N1     HID                // 256
#define K2     HID                // 256
#define N2     (NREL * F_OUT)     // 1152
#define SCAN_CHUNK 1024
#define NBLKN  ((NNODES + SCAN_CHUNK - 1) / SCAN_CHUNK)   // 49
#define RANGE   12500             // 50 KB LDS window -> 3 blocks/CU
#define NRANGE  4                 // RANGE*NRANGE = NNODES
#define NCHUNK  8                 // dst chunks (ordering granularity)
#define CHUNKE  (NEDGES / NCHUNK)   // 31250

typedef __attribute__((ext_vector_type(8))) short bf16x8;
typedef __attribute__((ext_vector_type(4))) float f32x4;
typedef __attribute__((ext_vector_type(4))) unsigned short u16x4;

__device__ __forceinline__ float b2f(ushort u) { return __uint_as_float(((unsigned)u) << 16); }
__device__ __forceinline__ ushort f2b(float f) {
    unsigned u = __float_as_uint(f);
    unsigned r = (u + 0x7fffu + ((u >> 16) & 1u)) >> 16;
    return (ushort)r;
}
__device__ __forceinline__ void gload16(const void* g, void* l) {
    __builtin_amdgcn_global_load_lds((const __attribute__((address_space(1))) void*)g,
                                     (__attribute__((address_space(3))) void*)l, 16, 0, 0);
}
// non-temporal stores via native clang vectors (HIP_vector_type structs are rejected)
__device__ __forceinline__ void nt_store_u4(ushort* p, ushort4 v) {
    u16x4 nv = {v.x, v.y, v.z, v.w};
    __builtin_nontemporal_store(nv, reinterpret_cast<u16x4*>(p));
}
__device__ __forceinline__ void nt_store_f4(float* p, float4 v) {
    f32x4 nv = {v.x, v.y, v.z, v.w};
    __builtin_nontemporal_store(nv, reinterpret_cast<f32x4*>(p));
}

// ---------------- LDS-privatized histogram (dst and src share this) ----------------
__global__ __launch_bounds__(256) void hist_kernel(const int* __restrict__ idx,
                                                   int* __restrict__ cnt) {
    __shared__ int h[RANGE];
    int c = blockIdx.x, rg = blockIdx.y, r = blockIdx.z;
    int lo = rg * RANGE;
    for (int i = threadIdx.x; i < RANGE; i += 256) h[i] = 0;
    __syncthreads();
    const int2* base = reinterpret_cast<const int2*>(idx + (size_t)r * NEDGES + (size_t)c * CHUNKE);
    for (int i = threadIdx.x; i < CHUNKE / 2; i += 256) {
        int2 v = base[i];
        int a = v.x - lo; if ((unsigned)a < RANGE) atomicAdd(&h[a], 1);
        int b = v.y - lo; if ((unsigned)b < RANGE) atomicAdd(&h[b], 1);
    }
    __syncthreads();
    int* outp = cnt + (size_t)c * RN + (size_t)r * NNODES + lo;
    for (int i = threadIdx.x; i < RANGE; i += 256) outp[i] = h[i];
}

// ---------------- fused: degree sums + norm tables + block sums (scanA) ----------------
__global__ __launch_bounds__(256) void scanA2_kernel(const int* __restrict__ cnt_s,
                                                     const int* __restrict__ cnt_d,
                                                     float* __restrict__ disS2,
                                                     float* __restrict__ disD2,
                                                     int* __restrict__ degN,
                                                     int* __restrict__ bsums) {
    __shared__ int sh[256];
    int t = threadIdx.x;
    int partial = 0;
    #pragma unroll
    for (int j = 0; j < 4; ++j) {
        int n = blockIdx.x * SCAN_CHUNK + j * 256 + t;
        if (n < NNODES) {
            int dN = 0;
            #pragma unroll
            for (int r = 0; r < NREL; ++r) {
                int d = 0, s = 0;
                #pragma unroll
                for (int c = 0; c < NCHUNK; ++c) {
                    d += cnt_d[(size_t)c * RN + r * NNODES + n];
                    s += cnt_s[(size_t)c * RN + r * NNODES + n];
                }
                disS2[(r << 16) + n] = rsqrtf((float)(s < 1 ? 1 : s));
                disD2[(r << 16) + n] = rsqrtf((float)(d < 1 ? 1 : d));
                dN += d;
            }
            degN[n] = dN;
            partial += dN;
        }
    }
    sh[t] = partial;
    __syncthreads();
    for (int off = 128; off > 0; off >>= 1) {
        if (t < off) sh[t] += sh[t + off];
        __syncthreads();
    }
    if (t == 0) bsums[blockIdx.x] = sh[0];
}

__global__ __launch_bounds__(512) void scanB_kernel(int* __restrict__ bsums) {
    __shared__ int sh[512];
    int t = threadIdx.x;
    int v = (t < NBLKN) ? bsums[t] : 0;
    sh[t] = v;
    __syncthreads();
    for (int off = 1; off < 512; off <<= 1) {
        int u = (t >= off) ? sh[t - off] : 0;
        __syncthreads();
        sh[t] += u;
        __syncthreads();
    }
    if (t < NBLKN) bsums[t] = sh[t] - v;
}

// ---------------- fused: node-offset scan + per-(rel,chunk) cursor bases ----------------
__global__ __launch_bounds__(256) void scanC2_kernel(const int* __restrict__ degN,
                                                     const int* __restrict__ bsums,
                                                     const int* __restrict__ cnt_d,
                                                     int* __restrict__ offsN,
                                                     int* __restrict__ cbase) {
    __shared__ int sh[256];
    __shared__ int offs_l[SCAN_CHUNK];
    int t = threadIdx.x;
    int base = blockIdx.x * SCAN_CHUNK + t * 4;
    int v[4]; int s = 0;
    #pragma unroll
    for (int j = 0; j < 4; ++j) { int i = base + j; v[j] = (i < NNODES) ? degN[i] : 0; s += v[j]; }
    sh[t] = s;
    __syncthreads();
    for (int off = 1; off < 256; off <<= 1) {
        int u = (t >= off) ? sh[t - off] : 0;
        __syncthreads();
        sh[t] += u;
        __syncthreads();
    }
    int p = bsums[blockIdx.x] + sh[t] - s;
    #pragma unroll
    for (int j = 0; j < 4; ++j) {
        int i = base + j;
        if (i < NNODES) offsN[i] = p;
        offs_l[t * 4 + j] = p;
        p += v[j];
    }
    __syncthreads();
    // chunkbase phase: strided node assignment for coalesced cnt_d reads
    #pragma unroll
    for (int j = 0; j < 4; ++j) {
        int li = j * 256 + t;
        int n = blockIdx.x * SCAN_CHUNK + li;
        if (n < NNODES) {
            int p2 = offs_l[li];
            #pragma unroll
            for (int r = 0; r < NREL; ++r)
                #pragma unroll
                for (int c = 0; c < NCHUNK; ++c) {
                    size_t idx = (size_t)c * RN + r * NNODES + n;
                    cbase[idx] = p2;
                    p2 += cnt_d[idx];
                }
        }
    }
}

// ---------------- merged-CSR fill with LDS cursors: esrcB = (r<<16)|s ----------------
__global__ __launch_bounds__(256) void fill2_kernel(const int* __restrict__ src,
                                                    const int* __restrict__ dst,
                                                    const int* __restrict__ cbase,
                                                    int* __restrict__ esrcB) {
    __shared__ int cur[RANGE];
    int c = blockIdx.x, rg = blockIdx.y, r = blockIdx.z;
    int lo = rg * RANGE;
    const int* cb = cbase + (size_t)c * RN + (size_t)r * NNODES + lo;
    for (int i = threadIdx.x; i < RANGE; i += 256) cur[i] = cb[i];
    __syncthreads();
    int vBb = r << 16;
    const int2* sb = reinterpret_cast<const int2*>(src + (size_t)r * NEDGES + (size_t)c * CHUNKE);
    const int2* db = reinterpret_cast<const int2*>(dst + (size_t)r * NEDGES + (size_t)c * CHUNKE);
    for (int i = threadIdx.x; i < CHUNKE / 2; i += 256) {
        int2 s2 = sb[i];
        int2 d2 = db[i];
        int a = d2.x - lo;
        if ((unsigned)a < RANGE) { int pos = atomicAdd(&cur[a], 1); esrcB[pos] = vBb | s2.x; }
        int b = d2.y - lo;
        if ((unsigned)b < RANGE) { int pos = atomicAdd(&cur[b], 1); esrcB[pos] = vBb | s2.y; }
    }
}

// ---------------- conversions ----------------
__global__ void to_bf16_kernel(const float* __restrict__ in, ushort* __restrict__ out, int n4) {
    int i = blockIdx.x * blockDim.x + threadIdx.x;
    if (i >= n4) return;
    float4 v = reinterpret_cast<const float4*>(in)[i];
    ushort4 o; o.x = f2b(v.x); o.y = f2b(v.y); o.z = f2b(v.z); o.w = f2b(v.w);
    reinterpret_cast<ushort4*>(out)[i] = o;
}

// fused weight transpose + bias sums
#define W1SZ (NREL * F_IN * HID)
#define W2SZ (NREL * HID * F_OUT)
__global__ void wprep_kernel(const float* __restrict__ W1, const float* __restrict__ W2,
                             const float* __restrict__ b1, const float* __restrict__ b2,
                             ushort* __restrict__ W1t, ushort* __restrict__ W2t,
                             float* __restrict__ bsum1, float* __restrict__ bsum2) {
    int idx = blockIdx.x * blockDim.x + threadIdx.x;
    if (idx < W1SZ) {
        int r = idx / (F_IN * HID);
        int k = (idx / HID) % F_IN;
        int j = idx % HID;
        W1t[(size_t)j * K1 + r * F_IN + k] = f2b(W1[idx]);
        return;
    }
    idx -= W1SZ;
    if (idx < W2SZ) {
        int r = idx / (HID * F_OUT);
        int k = (idx / F_OUT) % HID;
        int j = idx % F_OUT;
        W2t[(size_t)(r * F_OUT + j) * K2 + k] = f2b(W2[idx]);
        return;
    }
    idx -= W2SZ;
    if (idx < HID) { float s = 0; for (int r = 0; r < NREL; ++r) s += b1[r * HID + idx]; bsum1[idx] = s; }
    else if (idx < HID + F_OUT) {
        int i = idx - HID;
        float s = 0; for (int r = 0; r < NREL; ++r) s += b2[r * F_OUT + i]; bsum2[i] = s;
    }
}

// ---------------- layer-1 gather: sequential per-relation runs, 4-way ILP ----------------
// NT-stores for buf (115MB stream) so x_bf (12.8MB) stays L3-resident.
__global__ __launch_bounds__(256) void gather1_kernel(const ushort* __restrict__ x_bf,
                                                      const int* __restrict__ esrcB,
                                                      const int* __restrict__ cbase0,
                                                      const int* __restrict__ offsN,
                                                      const int* __restrict__ degN,
                                                      const float* __restrict__ disS2,
                                                      const float* __restrict__ disD2,
                                                      ushort* __restrict__ buf) {
    int lane = threadIdx.x & 31, grp = threadIdx.x >> 5;
    int n = blockIdx.x * 8 + grp;
    if (n >= NNODES) return;
    const ushort* xb = x_bf + lane * 4;
    int b[NREL + 1];
    #pragma unroll
    for (int r = 0; r < NREL; ++r) b[r] = cbase0[r * NNODES + n];
    b[NREL] = offsN[n] + degN[n];
    #pragma unroll
    for (int r = 0; r < NREL; ++r) {
        int st = b[r], en = b[r + 1];
        float4 a0 = {0,0,0,0}, a1 = {0,0,0,0}, a2 = {0,0,0,0}, a3 = {0,0,0,0};
        int k = st;
        if (r < 6) {
            for (; k + 4 <= en; k += 4) {
                int v0 = esrcB[k] & 0xFFFF, v1 = esrcB[k+1] & 0xFFFF;
                int v2 = esrcB[k+2] & 0xFFFF, v3 = esrcB[k+3] & 0xFFFF;
                ushort4 q0 = *reinterpret_cast<const ushort4*>(&xb[(size_t)v0 * F_IN]);
                ushort4 q1 = *reinterpret_cast<const ushort4*>(&xb[(size_t)v1 * F_IN]);
                ushort4 q2 = *reinterpret_cast<const ushort4*>(&xb[(size_t)v2 * F_IN]);
                ushort4 q3 = *reinterpret_cast<const ushort4*>(&xb[(size_t)v3 * F_IN]);
                a0.x += b2f(q0.x); a0.y += b2f(q0.y); a0.z += b2f(q0.z); a0.w += b2f(q0.w);
                a1.x += b2f(q1.x); a1.y += b2f(q1.y); a1.z += b2f(q1.z); a1.w += b2f(q1.w);
                a2.x += b2f(q2.x); a2.y += b2f(q2.y); a2.z += b2f(q2.z); a2.w += b2f(q2.w);
                a3.x += b2f(q3.x); a3.y += b2f(q3.y); a3.z += b2f(q3.z); a3.w += b2f(q3.w);
            }
            for (; k < en; ++k) {
                int v = esrcB[k] & 0xFFFF;
                ushort4 q = *reinterpret_cast<const ushort4*>(&xb[(size_t)v * F_IN]);
                a0.x += b2f(q.x); a0.y += b2f(q.y); a0.z += b2f(q.z); a0.w += b2f(q.w);
            }
        } else {
            for (; k + 4 <= en; k += 4) {
                int w0 = esrcB[k], w1 = esrcB[k+1], w2 = esrcB[k+2], w3 = esrcB[k+3];
                int v0 = w0 & 0xFFFF, v1 = w1 & 0xFFFF, v2 = w2 & 0xFFFF, v3 = w3 & 0xFFFF;
                ushort4 q0 = *reinterpret_cast<const ushort4*>(&xb[(size_t)v0 * F_IN]);
                ushort4 q1 = *reinterpret_cast<const ushort4*>(&xb[(size_t)v1 * F_IN]);
                ushort4 q2 = *reinterpret_cast<const ushort4*>(&xb[(size_t)v2 * F_IN]);
                ushort4 q3 = *reinterpret_cast<const ushort4*>(&xb[(size_t)v3 * F_IN]);
                float c0 = disS2[w0], c1 = disS2[w1], c2 = disS2[w2], c3 = disS2[w3];
                a0.x += b2f(q0.x)*c0; a0.y += b2f(q0.y)*c0; a0.z += b2f(q0.z)*c0; a0.w += b2f(q0.w)*c0;
                a1.x += b2f(q1.x)*c1; a1.y += b2f(q1.y)*c1; a1.z += b2f(q1.z)*c1; a1.w += b2f(q1.w)*c1;
                a2.x += b2f(q2.x)*c2; a2.y += b2f(q2.y)*c2; a2.z += b2f(q2.z)*c2; a2.w += b2f(q2.w)*c2;
                a3.x += b2f(q3.x)*c3; a3.y += b2f(q3.y)*c3; a3.z += b2f(q3.z)*c3; a3.w += b2f(q3.w)*c3;
            }
            for (; k < en; ++k) {
                int w = esrcB[k];
                int v = w & 0xFFFF;
                ushort4 q = *reinterpret_cast<const ushort4*>(&xb[(size_t)v * F_IN]);
                float cc = disS2[w];
                a0.x += b2f(q.x)*cc; a0.y += b2f(q.y)*cc; a0.z += b2f(q.z)*cc; a0.w += b2f(q.w)*cc;
            }
            float dd = disD2[(r << 16) + n];
            a0.x *= dd; a0.y *= dd; a0.z *= dd; a0.w *= dd;
            a1.x *= dd; a1.y *= dd; a1.z *= dd; a1.w *= dd;
            a2.x *= dd; a2.y *= dd; a2.z *= dd; a2.w *= dd;
            a3.x *= dd; a3.y *= dd; a3.z *= dd; a3.w *= dd;
        }
        ushort4 o;
        o.x = f2b(a0.x + a1.x + a2.x + a3.x);
        o.y = f2b(a0.y + a1.y + a2.y + a3.y);
        o.z = f2b(a0.z + a1.z + a2.z + a3.z);
        o.w = f2b(a0.w + a1.w + a2.w + a3.w);
        nt_store_u4(&buf[(size_t)n * K1 + r * F_IN + lane * 4], o);
    }
}

// ---------------- layer-2 gather: merged list (deg~45), unroll-8 MLP ----------------
// NT-store out (never re-read), NT-load index stream.
__global__ __launch_bounds__(256) void gather2_kernel(const ushort* __restrict__ Tp,
                                                      const int* __restrict__ esrcB,
                                                      const int* __restrict__ offsN,
                                                      const int* __restrict__ degN,
                                                      const float* __restrict__ disD2,
                                                      const float* __restrict__ bsum2,
                                                      float* __restrict__ out) {
    int lane = threadIdx.x & 31, grp = threadIdx.x >> 5;
    int n = blockIdx.x * 8 + grp;
    if (n >= NNODES) return;
    int st = offsN[n], en = st + degN[n];
    float4 acc = *reinterpret_cast<const float4*>(&bsum2[lane * 4]);
    const ushort* tb = Tp + lane * 4;
    int k = st;
#define TROW(v) ((size_t)(((v) >> 16) * NNODES + ((v) & 0xFFFF)) * F_OUT)
#define DSC(v)  disD2[((v) & 0xFFFF0000) + n]
    for (; k + 8 <= en; k += 8) {
        int v0 = __builtin_nontemporal_load(&esrcB[k + 0]);
        int v1 = __builtin_nontemporal_load(&esrcB[k + 1]);
        int v2 = __builtin_nontemporal_load(&esrcB[k + 2]);
        int v3 = __builtin_nontemporal_load(&esrcB[k + 3]);
        int v4 = __builtin_nontemporal_load(&esrcB[k + 4]);
        int v5 = __builtin_nontemporal_load(&esrcB[k + 5]);
        int v6 = __builtin_nontemporal_load(&esrcB[k + 6]);
        int v7 = __builtin_nontemporal_load(&esrcB[k + 7]);
        ushort4 q0 = *reinterpret_cast<const ushort4*>(&tb[TROW(v0)]);
        ushort4 q1 = *reinterpret_cast<const ushort4*>(&tb[TROW(v1)]);
        ushort4 q2 = *reinterpret_cast<const ushort4*>(&tb[TROW(v2)]);
        ushort4 q3 = *reinterpret_cast<const ushort4*>(&tb[TROW(v3)]);
        ushort4 q4 = *reinterpret_cast<const ushort4*>(&tb[TROW(v4)]);
        ushort4 q5 = *reinterpret_cast<const ushort4*>(&tb[TROW(v5)]);
        ushort4 q6 = *reinterpret_cast<const ushort4*>(&tb[TROW(v6)]);
        ushort4 q7 = *reinterpret_cast<const ushort4*>(&tb[TROW(v7)]);
        float s0 = DSC(v0), s1 = DSC(v1), s2 = DSC(v2), s3 = DSC(v3);
        float s4 = DSC(v4), s5 = DSC(v5), s6 = DSC(v6), s7 = DSC(v7);
        acc.x += b2f(q0.x)*s0; acc.y += b2f(q0.y)*s0; acc.z += b2f(q0.z)*s0; acc.w += b2f(q0.w)*s0;
        acc.x += b2f(q1.x)*s1; acc.y += b2f(q1.y)*s1; acc.z += b2f(q1.z)*s1; acc.w += b2f(q1.w)*s1;
        acc.x += b2f(q2.x)*s2; acc.y += b2f(q2.y)*s2; acc.z += b2f(q2.z)*s2; acc.w += b2f(q2.w)*s2;
        acc.x += b2f(q3.x)*s3; acc.y += b2f(q3.y)*s3; acc.z += b2f(q3.z)*s3; acc.w += b2f(q3.w)*s3;
        acc.x += b2f(q4.x)*s4; acc.y += b2f(q4.y)*s4; acc.z += b2f(q4.z)*s4; acc.w += b2f(q4.w)*s4;
        acc.x += b2f(q5.x)*s5; acc.y += b2f(q5.y)*s5; acc.z += b2f(q5.z)*s5; acc.w += b2f(q5.w)*s5;
        acc.x += b2f(q6.x)*s6; acc.y += b2f(q6.y)*s6; acc.z += b2f(q6.z)*s6; acc.w += b2f(q6.w)*s6;
        acc.x += b2f(q7.x)*s7; acc.y += b2f(q7.y)*s7; acc.z += b2f(q7.z)*s7; acc.w += b2f(q7.w)*s7;
    }
    for (; k < en; ++k) {
        int v = esrcB[k];
        ushort4 q = *reinterpret_cast<const ushort4*>(&tb[TROW(v)]);
        float sc = DSC(v);
        acc.x += b2f(q.x)*sc; acc.y += b2f(q.y)*sc; acc.z += b2f(q.z)*sc; acc.w += b2f(q.w)*sc;
    }
#undef TROW
#undef DSC
    acc.x = acc.x > 0.f ? acc.x : 0.01f * acc.x;
    acc.y = acc.y > 0.f ? acc.y : 0.01f * acc.y;
    acc.z = acc.z > 0.f ? acc.z : 0.01f * acc.z;
    acc.w = acc.w > 0.f ? acc.w : 0.01f * acc.w;
    nt_store_f4(&out[(size_t)n * F_OUT + lane * 4], acc);
}

// ---------------- bf16 MFMA GEMM: C = A[M][KDIM] @ Bt[NOUT][KDIM]^T ----------------
template<int KDIM, int NOUT, int EPI>
__global__ __launch_bounds__(256) void gemm_bf16(const ushort* __restrict__ A, int Astride,
                                                 const ushort* __restrict__ Bt, int Bstride,
                                                 ushort* __restrict__ C,
                                                 const float* __restrict__ aux) {
    __shared__ ushort Al[128 * 64];
    __shared__ ushort Bl[128 * 64];
    const int tid = threadIdx.x;
    const int lane = tid & 63;
    const int w = tid >> 6;
    const int wm = w >> 1, wn = w & 1;
    const int m0 = blockIdx.y * 128, n0 = blockIdx.x * 128;

    const int r8 = lane >> 3;
    const int sl = (lane & 7) ^ r8;
    const char* Ab = (const char*)A + (size_t)(m0 + w * 32 + r8) * Astride + sl * 16;
    const char* Bb = (const char*)Bt + (size_t)(n0 + w * 32 + r8) * Bstride + sl * 16;

    f32x4 acc[4][4];
    #pragma unroll
    for (int i = 0; i < 4; ++i)
        #pragma unroll
        for (int j = 0; j < 4; ++j) acc[i][j] = (f32x4){0.f, 0.f, 0.f, 0.f};

    for (int kt = 0; kt < KDIM / 64; ++kt) {
        const size_t kb = (size_t)kt * 128;
        #pragma unroll
        for (int i = 0; i < 4; ++i) {
            gload16(Ab + (size_t)(i * 8) * Astride + kb, &Al[(w * 32 + i * 8) * 64]);
            gload16(Bb + (size_t)(i * 8) * Bstride + kb, &Bl[(w * 32 + i * 8) * 64]);
        }
        __syncthreads();
        bf16x8 a[2][4], b[2][4];
        #pragma unroll
        for (int ks = 0; ks < 2; ++ks) {
            #pragma unroll
            for (int m = 0; m < 4; ++m) {
                int row = wm * 64 + m * 16 + (lane & 15);
                int slot = (ks * 4 + (lane >> 4)) ^ (row & 7);
                a[ks][m] = *reinterpret_cast<const bf16x8*>(&Al[row * 64 + slot * 8]);
                int rowb = wn * 64 + m * 16 + (lane & 15);
                int slotb = (ks * 4 + (lane >> 4)) ^ (rowb & 7);
                b[ks][m] = *reinterpret_cast<const bf16x8*>(&Bl[rowb * 64 + slotb * 8]);
            }
        }
        #pragma unroll
        for (int ks = 0; ks < 2; ++ks)
            #pragma unroll
            for (int m = 0; m < 4; ++m)
                #pragma unroll
                for (int n = 0; n < 4; ++n)
                    acc[m][n] = __builtin_amdgcn_mfma_f32_16x16x32_bf16(a[ks][m], b[ks][n], acc[m][n], 0, 0, 0);
        __syncthreads();
    }
    if (EPI == 1) {
        #pragma unroll
        for (int m = 0; m < 4; ++m) {
            int rbase = m0 + wm * 64 + m * 16 + (lane >> 4) * 4;
            #pragma unroll
            for (int n = 0; n < 4; ++n) {
                int col = n0 + wn * 64 + n * 16 + (lane & 15);
                float bb = aux[col];
                #pragma unroll
                for (int q = 0; q < 4; ++q) {
                    int r = rbase + q;
                    if (r < NNODES) {
                        float v = acc[m][n][q] + bb;
                        v = v > 0.f ? v : 0.01f * v;
                        C[(size_t)r * NOUT + col] = f2b(v);
                    }
                }
            }
        }
    } else {
        const int rel = blockIdx.x;   // N2/128 = 9 relations
        const float* dsr = aux + ((size_t)rel << 16);
        #pragma unroll
        for (int m = 0; m < 4; ++m) {
            int rbase = m0 + wm * 64 + m * 16 + (lane >> 4) * 4;
            #pragma unroll
            for (int n = 0; n < 4; ++n) {
                int cl = wn * 64 + n * 16 + (lane & 15);   // local col 0..127
                #pragma unroll
                for (int q = 0; q < 4; ++q) {
                    int r = rbase + q;
                    if (r < NNODES)
                        C[((size_t)rel * NNODES + r) * F_OUT + cl] = f2b(acc[m][n][q] * dsr[r]);
                }
            }
        }
    }
}

extern "C" void kernel_launch(void* const* d_in, const int* in_sizes, int n_in,
                              void* d_out, int out_size, void* d_ws, size_t ws_size,
                              hipStream_t stream) {
    const float* x   = (const float*)d_in[0];
    const int*   src = (const int*)d_in[1];
    const int*   dst = (const int*)d_in[2];
    const float* W1  = (const float*)d_in[3];
    const float* b1  = (const float*)d_in[4];
    const float* W2  = (const float*)d_in[5];
    const float* b2  = (const float*)d_in[6];
    float* out = (float*)d_out;

    // ---- workspace layout (esrcB aliases cnt_d; Tpack aliases buf) ----
    char* p = (char*)d_ws;
    int*    cnt_d = (int*)p;    p += (size_t)NCHUNK * RN * sizeof(int);     // 14.4MB
    int*    esrcB = cnt_d;      // alias: cnt_d dead after scanC2, esrcB written in fill2
    int*    cbase = (int*)p;    p += (size_t)NCHUNK * RN * sizeof(int);     // 14.4MB
    int*    cnt_s = (int*)p;    p += (size_t)NCHUNK * RN * sizeof(int);     // 14.4MB
    float*  disS2 = (float*)p;  p += (size_t)(NREL << 16) * sizeof(float);  // 2.36MB
    float*  disD2 = (float*)p;  p += (size_t)(NREL << 16) * sizeof(float);  // 2.36MB
    int*    degN  = (int*)p;    p += (size_t)NNODES * sizeof(int);
    int*    offsN = (int*)p;    p += (size_t)NNODES * sizeof(int);
    int*    bsums = (int*)p;    p += (size_t)1024 * sizeof(int);
    float*  bsum1 = (float*)p;  p += (size_t)512 * sizeof(float);
    float*  bsum2 = (float*)p;  p += (size_t)512 * sizeof(float);
    ushort* x_bf  = (ushort*)p; p += (size_t)NNODES * F_IN * sizeof(ushort);   // 12.8MB
    ushort* W1t   = (ushort*)p; p += (size_t)N1 * K1 * sizeof(ushort);
    ushort* W2t   = (ushort*)p; p += (size_t)N2 * K2 * sizeof(ushort);
    ushort* h1_bf = (ushort*)p; p += (size_t)MPAD * HID * sizeof(ushort);      // 25.6MB
    ushort* buf   = (ushort*)p;   // [MPAD][K1] bf16 = 115.3MB
    ushort* Tpack = buf;          // alias: [9][NNODES][128] bf16

    dim3 hgrid(NCHUNK, NRANGE, NREL);   // 288 blocks @ 50KB LDS

    // ---- CSR build (merged by dst, r-major then chunk-order within node) ----
    hist_kernel<<<hgrid, 256, 0, stream>>>(dst, cnt_d);
    hist_kernel<<<hgrid, 256, 0, stream>>>(src, cnt_s);
    scanA2_kernel<<<NBLKN, 256, 0, stream>>>(cnt_s, cnt_d, disS2, disD2, degN, bsums);
    scanB_kernel<<<1, 512, 0, stream>>>(bsums);
    scanC2_kernel<<<NBLKN, 256, 0, stream>>>(degN, bsums, cnt_d, offsN, cbase);
    fill2_kernel<<<hgrid, 256, 0, stream>>>(src, dst, cbase, esrcB);

    // ---- precompute ----
    to_bf16_kernel<<<(NNODES * F_IN / 4 + 255) / 256, 256, 0, stream>>>(x, x_bf, NNODES * F_IN / 4);
    {
        int tot = W1SZ + W2SZ + HID + F_OUT;
        wprep_kernel<<<(tot + 255) / 256, 256, 0, stream>>>(W1, W2, b1, b2, W1t, W2t, bsum1, bsum2);
    }

    // ---- layer 1: gather (sequential per-relation, merged CSR) then one GEMM ----
    gather1_kernel<<<(NNODES + 7) / 8, 256, 0, stream>>>(x_bf, esrcB, cbase, offsN, degN,
                                                         disS2, disD2, buf);
    {
        dim3 g(N1 / 128, MPAD / 128);
        gemm_bf16<K1, N1, 1><<<g, 256, 0, stream>>>(buf, K1 * 2, W1t, K1 * 2, h1_bf, bsum1);
    }

    // ---- layer 2: weight-first GEMM (disS2 folded into epilogue) then merged gather ----
    {
        dim3 g(N2 / 128, MPAD / 128);
        gemm_bf16<K2, N2, 2><<<g, 256, 0, stream>>>(h1_bf, K2 * 2, W2t, K2 * 2, Tpack, disS2);
    }
    gather2_kernel<<<(NNODES + 7) / 8, 256, 0, stream>>>(Tpack, esrcB, offsN, degN, disD2, bsum2, out);
}

// Round 13
// 536.595 us; speedup vs baseline: 1.0137x; 1.0137x over previous
//
#include <hip/hip_runtime.h>
#include <math.h>

#define NNODES 50000
#define NEDGES 250000
#define NREL   9
#define F_IN   128
#define HID    256
#define F_OUT  128
#define RN     (NREL * NNODES)
#define RE     (NREL * NEDGES)
#define MPAD   50048              // 391*128
#define K1     (NREL * F_IN)      // 1152
#define N1     HID                // 256
#define K2     HID                // 256
#define N2     (NREL * F_OUT)     // 1152
#define SCAN_CHUNK 1024
#define NBLKN  ((NNODES + SCAN_CHUNK - 1) / SCAN_CHUNK)   // 49
#define RANGE   12500             // 50 KB LDS window -> 3 blocks/CU
#define NRANGE  4                 // RANGE*NRANGE = NNODES
#define NCHUNK  8                 // dst chunks (ordering granularity)
#define CHUNKE  (NEDGES / NCHUNK)   // 31250

typedef __attribute__((ext_vector_type(8))) short bf16x8;
typedef __attribute__((ext_vector_type(4))) float f32x4;

__device__ __forceinline__ float b2f(ushort u) { return __uint_as_float(((unsigned)u) << 16); }
__device__ __forceinline__ ushort f2b(float f) {
    unsigned u = __float_as_uint(f);
    unsigned r = (u + 0x7fffu + ((u >> 16) & 1u)) >> 16;
    return (ushort)r;
}
__device__ __forceinline__ void gload16(const void* g, void* l) {
    __builtin_amdgcn_global_load_lds((const __attribute__((address_space(1))) void*)g,
                                     (__attribute__((address_space(3))) void*)l, 16, 0, 0);
}

// ---------------- fused dst+src LDS-privatized histogram ----------------
__global__ __launch_bounds__(256) void hist2_kernel(const int* __restrict__ dstArr,
                                                    const int* __restrict__ srcArr,
                                                    int* __restrict__ cnt_d,
                                                    int* __restrict__ cnt_s) {
    __shared__ int h[RANGE];
    int c = blockIdx.x, rg = blockIdx.y, z = blockIdx.z;
    const int* idx = (z < NREL) ? dstArr : srcArr;
    int* cnt = (z < NREL) ? cnt_d : cnt_s;
    int r = (z < NREL) ? z : z - NREL;
    int lo = rg * RANGE;
    for (int i = threadIdx.x; i < RANGE; i += 256) h[i] = 0;
    __syncthreads();
    const int2* base = reinterpret_cast<const int2*>(idx + (size_t)r * NEDGES + (size_t)c * CHUNKE);
    for (int i = threadIdx.x; i < CHUNKE / 2; i += 256) {
        int2 v = base[i];
        int a = v.x - lo; if ((unsigned)a < RANGE) atomicAdd(&h[a], 1);
        int b = v.y - lo; if ((unsigned)b < RANGE) atomicAdd(&h[b], 1);
    }
    __syncthreads();
    int* outp = cnt + (size_t)c * RN + (size_t)r * NNODES + lo;
    for (int i = threadIdx.x; i < RANGE; i += 256) outp[i] = h[i];
}

// ---------------- fused: degree sums + norm tables + block sums (scanA) ----------------
__global__ __launch_bounds__(256) void scanA2_kernel(const int* __restrict__ cnt_s,
                                                     const int* __restrict__ cnt_d,
                                                     float* __restrict__ disS2,
                                                     float* __restrict__ disD2,
                                                     int* __restrict__ degN,
                                                     int* __restrict__ bsums) {
    __shared__ int sh[256];
    int t = threadIdx.x;
    int partial = 0;
    #pragma unroll
    for (int j = 0; j < 4; ++j) {
        int n = blockIdx.x * SCAN_CHUNK + j * 256 + t;
        if (n < NNODES) {
            int dN = 0;
            #pragma unroll
            for (int r = 0; r < NREL; ++r) {
                int d = 0, s = 0;
                #pragma unroll
                for (int c = 0; c < NCHUNK; ++c) {
                    d += cnt_d[(size_t)c * RN + r * NNODES + n];
                    s += cnt_s[(size_t)c * RN + r * NNODES + n];
                }
                disS2[(r << 16) + n] = rsqrtf((float)(s < 1 ? 1 : s));
                disD2[(r << 16) + n] = rsqrtf((float)(d < 1 ? 1 : d));
                dN += d;
            }
            degN[n] = dN;
            partial += dN;
        }
    }
    sh[t] = partial;
    __syncthreads();
    for (int off = 128; off > 0; off >>= 1) {
        if (t < off) sh[t] += sh[t + off];
        __syncthreads();
    }
    if (t == 0) bsums[blockIdx.x] = sh[0];
}

__global__ __launch_bounds__(512) void scanB_kernel(int* __restrict__ bsums) {
    __shared__ int sh[512];
    int t = threadIdx.x;
    int v = (t < NBLKN) ? bsums[t] : 0;
    sh[t] = v;
    __syncthreads();
    for (int off = 1; off < 512; off <<= 1) {
        int u = (t >= off) ? sh[t - off] : 0;
        __syncthreads();
        sh[t] += u;
        __syncthreads();
    }
    if (t < NBLKN) bsums[t] = sh[t] - v;
}

// ---------------- fused: node-offset scan + per-(rel,chunk) cursor bases ----------------
__global__ __launch_bounds__(256) void scanC2_kernel(const int* __restrict__ degN,
                                                     const int* __restrict__ bsums,
                                                     const int* __restrict__ cnt_d,
                                                     int* __restrict__ offsN,
                                                     int* __restrict__ cbase) {
    __shared__ int sh[256];
    __shared__ int offs_l[SCAN_CHUNK];
    int t = threadIdx.x;
    int base = blockIdx.x * SCAN_CHUNK + t * 4;
    int v[4]; int s = 0;
    #pragma unroll
    for (int j = 0; j < 4; ++j) { int i = base + j; v[j] = (i < NNODES) ? degN[i] : 0; s += v[j]; }
    sh[t] = s;
    __syncthreads();
    for (int off = 1; off < 256; off <<= 1) {
        int u = (t >= off) ? sh[t - off] : 0;
        __syncthreads();
        sh[t] += u;
        __syncthreads();
    }
    int p = bsums[blockIdx.x] + sh[t] - s;
    #pragma unroll
    for (int j = 0; j < 4; ++j) {
        int i = base + j;
        if (i < NNODES) offsN[i] = p;
        offs_l[t * 4 + j] = p;
        p += v[j];
    }
    __syncthreads();
    #pragma unroll
    for (int j = 0; j < 4; ++j) {
        int li = j * 256 + t;
        int n = blockIdx.x * SCAN_CHUNK + li;
        if (n < NNODES) {
            int p2 = offs_l[li];
            #pragma unroll
            for (int r = 0; r < NREL; ++r)
                #pragma unroll
                for (int c = 0; c < NCHUNK; ++c) {
                    size_t idx = (size_t)c * RN + r * NNODES + n;
                    cbase[idx] = p2;
                    p2 += cnt_d[idx];
                }
        }
    }
}

// ---------------- merged-CSR fill with LDS cursors: esrcB = (r<<16)|s ----------------
__global__ __launch_bounds__(256) void fill2_kernel(const int* __restrict__ src,
                                                    const int* __restrict__ dst,
                                                    const int* __restrict__ cbase,
                                                    int* __restrict__ esrcB) {
    __shared__ int cur[RANGE];
    int c = blockIdx.x, rg = blockIdx.y, r = blockIdx.z;
    int lo = rg * RANGE;
    const int* cb = cbase + (size_t)c * RN + (size_t)r * NNODES + lo;
    for (int i = threadIdx.x; i < RANGE; i += 256) cur[i] = cb[i];
    __syncthreads();
    int vBb = r << 16;
    const int2* sb = reinterpret_cast<const int2*>(src + (size_t)r * NEDGES + (size_t)c * CHUNKE);
    const int2* db = reinterpret_cast<const int2*>(dst + (size_t)r * NEDGES + (size_t)c * CHUNKE);
    for (int i = threadIdx.x; i < CHUNKE / 2; i += 256) {
        int2 s2 = sb[i];
        int2 d2 = db[i];
        int a = d2.x - lo;
        if ((unsigned)a < RANGE) { int pos = atomicAdd(&cur[a], 1); esrcB[pos] = vBb | s2.x; }
        int b = d2.y - lo;
        if ((unsigned)b < RANGE) { int pos = atomicAdd(&cur[b], 1); esrcB[pos] = vBb | s2.y; }
    }
}

// ---------------- conversions ----------------
__global__ void to_bf16_kernel(const float* __restrict__ in, ushort* __restrict__ out, int n4) {
    int i = blockIdx.x * blockDim.x + threadIdx.x;
    if (i >= n4) return;
    float4 v = reinterpret_cast<const float4*>(in)[i];
    ushort4 o; o.x = f2b(v.x); o.y = f2b(v.y); o.z = f2b(v.z); o.w = f2b(v.w);
    reinterpret_cast<ushort4*>(out)[i] = o;
}

// fused weight transpose + bias sums
#define W1SZ (NREL * F_IN * HID)
#define W2SZ (NREL * HID * F_OUT)
__global__ void wprep_kernel(const float* __restrict__ W1, const float* __restrict__ W2,
                             const float* __restrict__ b1, const float* __restrict__ b2,
                             ushort* __restrict__ W1t, ushort* __restrict__ W2t,
                             float* __restrict__ bsum1, float* __restrict__ bsum2) {
    int idx = blockIdx.x * blockDim.x + threadIdx.x;
    if (idx < W1SZ) {
        int r = idx / (F_IN * HID);
        int k = (idx / HID) % F_IN;
        int j = idx % HID;
        W1t[(size_t)j * K1 + r * F_IN + k] = f2b(W1[idx]);
        return;
    }
    idx -= W1SZ;
    if (idx < W2SZ) {
        int r = idx / (HID * F_OUT);
        int k = (idx / F_OUT) % HID;
        int j = idx % F_OUT;
        W2t[(size_t)(r * F_OUT + j) * K2 + k] = f2b(W2[idx]);
        return;
    }
    idx -= W2SZ;
    if (idx < HID) { float s = 0; for (int r = 0; r < NREL; ++r) s += b1[r * HID + idx]; bsum1[idx] = s; }
    else if (idx < HID + F_OUT) {
        int i = idx - HID;
        float s = 0; for (int r = 0; r < NREL; ++r) s += b2[r * F_OUT + i]; bsum2[i] = s;
    }
}

// ---------------- layer-1 gather: 16 lanes x 16B per row (2x MLP), 4-way unroll ----------------
__global__ __launch_bounds__(256) void gather1_kernel(const ushort* __restrict__ x_bf,
                                                      const int* __restrict__ esrcB,
                                                      const int* __restrict__ cbase0,
                                                      const int* __restrict__ offsN,
                                                      const int* __restrict__ degN,
                                                      const float* __restrict__ disS2,
                                                      const float* __restrict__ disD2,
                                                      ushort* __restrict__ buf) {
    int lane = threadIdx.x & 15, grp = threadIdx.x >> 4;   // 16 nodes/block
    int n = blockIdx.x * 16 + grp;
    if (n >= NNODES) return;
    const ushort* xb = x_bf + lane * 8;
    int b[NREL + 1];
    #pragma unroll
    for (int r = 0; r < NREL; ++r) b[r] = cbase0[r * NNODES + n];
    b[NREL] = offsN[n] + degN[n];
    #pragma unroll
    for (int r = 0; r < NREL; ++r) {
        int st = b[r], en = b[r + 1];
        float a0[8] = {}, a1[8] = {}, a2[8] = {}, a3[8] = {};
        int k = st;
        if (r < 6) {
            for (; k + 4 <= en; k += 4) {
                int v0 = esrcB[k] & 0xFFFF, v1 = esrcB[k+1] & 0xFFFF;
                int v2 = esrcB[k+2] & 0xFFFF, v3 = esrcB[k+3] & 0xFFFF;
                bf16x8 q0 = *reinterpret_cast<const bf16x8*>(&xb[(size_t)v0 * F_IN]);
                bf16x8 q1 = *reinterpret_cast<const bf16x8*>(&xb[(size_t)v1 * F_IN]);
                bf16x8 q2 = *reinterpret_cast<const bf16x8*>(&xb[(size_t)v2 * F_IN]);
                bf16x8 q3 = *reinterpret_cast<const bf16x8*>(&xb[(size_t)v3 * F_IN]);
                #pragma unroll
                for (int j = 0; j < 8; ++j) {
                    a0[j] += b2f((ushort)q0[j]); a1[j] += b2f((ushort)q1[j]);
                    a2[j] += b2f((ushort)q2[j]); a3[j] += b2f((ushort)q3[j]);
                }
            }
            for (; k < en; ++k) {
                int v = esrcB[k] & 0xFFFF;
                bf16x8 q = *reinterpret_cast<const bf16x8*>(&xb[(size_t)v * F_IN]);
                #pragma unroll
                for (int j = 0; j < 8; ++j) a0[j] += b2f((ushort)q[j]);
            }
        } else {
            for (; k + 4 <= en; k += 4) {
                int w0 = esrcB[k], w1 = esrcB[k+1], w2 = esrcB[k+2], w3 = esrcB[k+3];
                int v0 = w0 & 0xFFFF, v1 = w1 & 0xFFFF, v2 = w2 & 0xFFFF, v3 = w3 & 0xFFFF;
                bf16x8 q0 = *reinterpret_cast<const bf16x8*>(&xb[(size_t)v0 * F_IN]);
                bf16x8 q1 = *reinterpret_cast<const bf16x8*>(&xb[(size_t)v1 * F_IN]);
                bf16x8 q2 = *reinterpret_cast<const bf16x8*>(&xb[(size_t)v2 * F_IN]);
                bf16x8 q3 = *reinterpret_cast<const bf16x8*>(&xb[(size_t)v3 * F_IN]);
                float c0 = disS2[w0], c1 = disS2[w1], c2 = disS2[w2], c3 = disS2[w3];
                #pragma unroll
                for (int j = 0; j < 8; ++j) {
                    a0[j] += b2f((ushort)q0[j]) * c0; a1[j] += b2f((ushort)q1[j]) * c1;
                    a2[j] += b2f((ushort)q2[j]) * c2; a3[j] += b2f((ushort)q3[j]) * c3;
                }
            }
            for (; k < en; ++k) {
                int w = esrcB[k];
                int v = w & 0xFFFF;
                bf16x8 q = *reinterpret_cast<const bf16x8*>(&xb[(size_t)v * F_IN]);
                float cc = disS2[w];
                #pragma unroll
                for (int j = 0; j < 8; ++j) a0[j] += b2f((ushort)q[j]) * cc;
            }
            float dd = disD2[(r << 16) + n];
            #pragma unroll
            for (int j = 0; j < 8; ++j) {
                a0[j] *= dd; a1[j] *= dd; a2[j] *= dd; a3[j] *= dd;
            }
        }
        bf16x8 o;
        #pragma unroll
        for (int j = 0; j < 8; ++j) o[j] = (short)f2b(a0[j] + a1[j] + a2[j] + a3[j]);
        __builtin_nontemporal_store(o,
            reinterpret_cast<bf16x8*>(&buf[(size_t)n * K1 + r * F_IN + lane * 8]));
    }
}

// ---------------- layer-2 gather: 16 lanes x 16B per row, merged list, unroll-8 ----------------
__global__ __launch_bounds__(256) void gather2_kernel(const ushort* __restrict__ Tp,
                                                      const int* __restrict__ esrcB,
                                                      const int* __restrict__ offsN,
                                                      const int* __restrict__ degN,
                                                      const float* __restrict__ disD2,
                                                      const float* __restrict__ bsum2,
                                                      float* __restrict__ out) {
    int lane = threadIdx.x & 15, grp = threadIdx.x >> 4;   // 16 nodes/block
    int n = blockIdx.x * 16 + grp;
    if (n >= NNODES) return;
    int st = offsN[n], en = st + degN[n];
    float acc[8];
    #pragma unroll
    for (int j = 0; j < 8; ++j) acc[j] = bsum2[lane * 8 + j];
    const ushort* tb = Tp + lane * 8;
    int k = st;
#define TROW(v) ((size_t)(((v) >> 16) * NNODES + ((v) & 0xFFFF)) * F_OUT)
#define DSC(v)  disD2[((v) & 0xFFFF0000) + n]
    for (; k + 8 <= en; k += 8) {
        int v0 = __builtin_nontemporal_load(&esrcB[k + 0]);
        int v1 = __builtin_nontemporal_load(&esrcB[k + 1]);
        int v2 = __builtin_nontemporal_load(&esrcB[k + 2]);
        int v3 = __builtin_nontemporal_load(&esrcB[k + 3]);
        int v4 = __builtin_nontemporal_load(&esrcB[k + 4]);
        int v5 = __builtin_nontemporal_load(&esrcB[k + 5]);
        int v6 = __builtin_nontemporal_load(&esrcB[k + 6]);
        int v7 = __builtin_nontemporal_load(&esrcB[k + 7]);
        bf16x8 q0 = *reinterpret_cast<const bf16x8*>(&tb[TROW(v0)]);
        bf16x8 q1 = *reinterpret_cast<const bf16x8*>(&tb[TROW(v1)]);
        bf16x8 q2 = *reinterpret_cast<const bf16x8*>(&tb[TROW(v2)]);
        bf16x8 q3 = *reinterpret_cast<const bf16x8*>(&tb[TROW(v3)]);
        bf16x8 q4 = *reinterpret_cast<const bf16x8*>(&tb[TROW(v4)]);
        bf16x8 q5 = *reinterpret_cast<const bf16x8*>(&tb[TROW(v5)]);
        bf16x8 q6 = *reinterpret_cast<const bf16x8*>(&tb[TROW(v6)]);
        bf16x8 q7 = *reinterpret_cast<const bf16x8*>(&tb[TROW(v7)]);
        float s0 = DSC(v0), s1 = DSC(v1), s2 = DSC(v2), s3 = DSC(v3);
        float s4 = DSC(v4), s5 = DSC(v5), s6 = DSC(v6), s7 = DSC(v7);
        #pragma unroll
        for (int j = 0; j < 8; ++j) {
            acc[j] += b2f((ushort)q0[j]) * s0 + b2f((ushort)q1[j]) * s1
                    + b2f((ushort)q2[j]) * s2 + b2f((ushort)q3[j]) * s3
                    + b2f((ushort)q4[j]) * s4 + b2f((ushort)q5[j]) * s5
                    + b2f((ushort)q6[j]) * s6 + b2f((ushort)q7[j]) * s7;
        }
    }
    for (; k < en; ++k) {
        int v = esrcB[k];
        bf16x8 q = *reinterpret_cast<const bf16x8*>(&tb[TROW(v)]);
        float sc = DSC(v);
        #pragma unroll
        for (int j = 0; j < 8; ++j) acc[j] += b2f((ushort)q[j]) * sc;
    }
#undef TROW
#undef DSC
    f32x4 lo, hi;
    #pragma unroll
    for (int j = 0; j < 4; ++j) {
        float vl = acc[j],     vh = acc[j + 4];
        lo[j] = vl > 0.f ? vl : 0.01f * vl;
        hi[j] = vh > 0.f ? vh : 0.01f * vh;
    }
    float* op = &out[(size_t)n * F_OUT + lane * 8];
    __builtin_nontemporal_store(lo, reinterpret_cast<f32x4*>(op));
    __builtin_nontemporal_store(hi, reinterpret_cast<f32x4*>(op + 4));
}

// ---------------- bf16 MFMA GEMM: C = A[M][KDIM] @ Bt[NOUT][KDIM]^T ----------------
template<int KDIM, int NOUT, int EPI>
__global__ __launch_bounds__(256) void gemm_bf16(const ushort* __restrict__ A, int Astride,
                                                 const ushort* __restrict__ Bt, int Bstride,
                                                 ushort* __restrict__ C,
                                                 const float* __restrict__ aux) {
    __shared__ ushort Al[128 * 64];
    __shared__ ushort Bl[128 * 64];
    const int tid = threadIdx.x;
    const int lane = tid & 63;
    const int w = tid >> 6;
    const int wm = w >> 1, wn = w & 1;
    const int m0 = blockIdx.y * 128, n0 = blockIdx.x * 128;

    const int r8 = lane >> 3;
    const int sl = (lane & 7) ^ r8;
    const char* Ab = (const char*)A + (size_t)(m0 + w * 32 + r8) * Astride + sl * 16;
    const char* Bb = (const char*)Bt + (size_t)(n0 + w * 32 + r8) * Bstride + sl * 16;

    f32x4 acc[4][4];
    #pragma unroll
    for (int i = 0; i < 4; ++i)
        #pragma unroll
        for (int j = 0; j < 4; ++j) acc[i][j] = (f32x4){0.f, 0.f, 0.f, 0.f};

    for (int kt = 0; kt < KDIM / 64; ++kt) {
        const size_t kb = (size_t)kt * 128;
        #pragma unroll
        for (int i = 0; i < 4; ++i) {
            gload16(Ab + (size_t)(i * 8) * Astride + kb, &Al[(w * 32 + i * 8) * 64]);
            gload16(Bb + (size_t)(i * 8) * Bstride + kb, &Bl[(w * 32 + i * 8) * 64]);
        }
        __syncthreads();
        bf16x8 a[2][4], b[2][4];
        #pragma unroll
        for (int ks = 0; ks < 2; ++ks) {
            #pragma unroll
            for (int m = 0; m < 4; ++m) {
                int row = wm * 64 + m * 16 + (lane & 15);
                int slot = (ks * 4 + (lane >> 4)) ^ (row & 7);
                a[ks][m] = *reinterpret_cast<const bf16x8*>(&Al[row * 64 + slot * 8]);
                int rowb = wn * 64 + m * 16 + (lane & 15);
                int slotb = (ks * 4 + (lane >> 4)) ^ (rowb & 7);
                b[ks][m] = *reinterpret_cast<const bf16x8*>(&Bl[rowb * 64 + slotb * 8]);
            }
        }
        #pragma unroll
        for (int ks = 0; ks < 2; ++ks)
            #pragma unroll
            for (int m = 0; m < 4; ++m)
                #pragma unroll
                for (int n = 0; n < 4; ++n)
                    acc[m][n] = __builtin_amdgcn_mfma_f32_16x16x32_bf16(a[ks][m], b[ks][n], acc[m][n], 0, 0, 0);
        __syncthreads();
    }
    if (EPI == 1) {
        #pragma unroll
        for (int m = 0; m < 4; ++m) {
            int rbase = m0 + wm * 64 + m * 16 + (lane >> 4) * 4;
            #pragma unroll
            for (int n = 0; n < 4; ++n) {
                int col = n0 + wn * 64 + n * 16 + (lane & 15);
                float bb = aux[col];
                #pragma unroll
                for (int q = 0; q < 4; ++q) {
                    int r = rbase + q;
                    if (r < NNODES) {
                        float v = acc[m][n][q] + bb;
                        v = v > 0.f ? v : 0.01f * v;
                        C[(size_t)r * NOUT + col] = f2b(v);
                    }
                }
            }
        }
    } else {
        const int rel = blockIdx.x;   // N2/128 = 9 relations
        const float* dsr = aux + ((size_t)rel << 16);
        #pragma unroll
        for (int m = 0; m < 4; ++m) {
            int rbase = m0 + wm * 64 + m * 16 + (lane >> 4) * 4;
            #pragma unroll
            for (int n = 0; n < 4; ++n) {
                int cl = wn * 64 + n * 16 + (lane & 15);   // local col 0..127
                #pragma unroll
                for (int q = 0; q < 4; ++q) {
                    int r = rbase + q;
                    if (r < NNODES)
                        C[((size_t)rel * NNODES + r) * F_OUT + cl] = f2b(acc[m][n][q] * dsr[r]);
                }
            }
        }
    }
}

extern "C" void kernel_launch(void* const* d_in, const int* in_sizes, int n_in,
                              void* d_out, int out_size, void* d_ws, size_t ws_size,
                              hipStream_t stream) {
    const float* x   = (const float*)d_in[0];
    const int*   src = (const int*)d_in[1];
    const int*   dst = (const int*)d_in[2];
    const float* W1  = (const float*)d_in[3];
    const float* b1  = (const float*)d_in[4];
    const float* W2  = (const float*)d_in[5];
    const float* b2  = (const float*)d_in[6];
    float* out = (float*)d_out;

    // ---- workspace layout (esrcB aliases cnt_d; Tpack aliases buf) ----
    char* p = (char*)d_ws;
    int*    cnt_d = (int*)p;    p += (size_t)NCHUNK * RN * sizeof(int);     // 14.4MB
    int*    esrcB = cnt_d;      // alias: cnt_d dead after scanC2, esrcB written in fill2
    int*    cbase = (int*)p;    p += (size_t)NCHUNK * RN * sizeof(int);     // 14.4MB
    int*    cnt_s = (int*)p;    p += (size_t)NCHUNK * RN * sizeof(int);     // 14.4MB
    float*  disS2 = (float*)p;  p += (size_t)(NREL << 16) * sizeof(float);  // 2.36MB
    float*  disD2 = (float*)p;  p += (size_t)(NREL << 16) * sizeof(float);  // 2.36MB
    int*    degN  = (int*)p;    p += (size_t)NNODES * sizeof(int);
    int*    offsN = (int*)p;    p += (size_t)NNODES * sizeof(int);
    int*    bsums = (int*)p;    p += (size_t)1024 * sizeof(int);
    float*  bsum1 = (float*)p;  p += (size_t)512 * sizeof(float);
    float*  bsum2 = (float*)p;  p += (size_t)512 * sizeof(float);
    ushort* x_bf  = (ushort*)p; p += (size_t)NNODES * F_IN * sizeof(ushort);   // 12.8MB
    ushort* W1t   = (ushort*)p; p += (size_t)N1 * K1 * sizeof(ushort);
    ushort* W2t   = (ushort*)p; p += (size_t)N2 * K2 * sizeof(ushort);
    ushort* h1_bf = (ushort*)p; p += (size_t)MPAD * HID * sizeof(ushort);      // 25.6MB
    ushort* buf   = (ushort*)p;   // [MPAD][K1] bf16 = 115.3MB
    ushort* Tpack = buf;          // alias: [9][NNODES][128] bf16

    // ---- CSR build (merged by dst, r-major then chunk-order within node) ----
    {
        dim3 gh(NCHUNK, NRANGE, 2 * NREL);
        hist2_kernel<<<gh, 256, 0, stream>>>(dst, src, cnt_d, cnt_s);
    }
    scanA2_kernel<<<NBLKN, 256, 0, stream>>>(cnt_s, cnt_d, disS2, disD2, degN, bsums);
    scanB_kernel<<<1, 512, 0, stream>>>(bsums);
    scanC2_kernel<<<NBLKN, 256, 0, stream>>>(degN, bsums, cnt_d, offsN, cbase);
    {
        dim3 gf(NCHUNK, NRANGE, NREL);
        fill2_kernel<<<gf, 256, 0, stream>>>(src, dst, cbase, esrcB);
    }

    // ---- precompute ----
    to_bf16_kernel<<<(NNODES * F_IN / 4 + 255) / 256, 256, 0, stream>>>(x, x_bf, NNODES * F_IN / 4);
    {
        int tot = W1SZ + W2SZ + HID + F_OUT;
        wprep_kernel<<<(tot + 255) / 256, 256, 0, stream>>>(W1, W2, b1, b2, W1t, W2t, bsum1, bsum2);
    }

    // ---- layer 1: gather (16-lane rows, merged CSR) then one GEMM ----
    gather1_kernel<<<(NNODES + 15) / 16, 256, 0, stream>>>(x_bf, esrcB, cbase, offsN, degN,
                                                           disS2, disD2, buf);
    {
        dim3 g(N1 / 128, MPAD / 128);
        gemm_bf16<K1, N1, 1><<<g, 256, 0, stream>>>(buf, K1 * 2, W1t, K1 * 2, h1_bf, bsum1);
    }

    // ---- layer 2: weight-first GEMM (disS2 folded into epilogue) then merged gather ----
    {
        dim3 g(N2 / 128, MPAD / 128);
        gemm_bf16<K2, N2, 2><<<g, 256, 0, stream>>>(h1_bf, K2 * 2, W2t, K2 * 2, Tpack, disS2);
    }
    gather2_kernel<<<(NNODES + 15) / 16, 256, 0, stream>>>(Tpack, esrcB, offsN, degN, disD2, bsum2, out);
}